// Round 2
// baseline (982.299 us; speedup 1.0000x reference)
//
#include <hip/hip_runtime.h>
#include <hip/hip_bf16.h>

namespace {

constexpr int N = 2048;
constexpr int D = 64;
constexpr float SCALE = 0.125f;   // D^-0.5, D=64
constexpr int LSTR = 72;          // LDS row stride in bf16 elems (64 + 8 pad -> 144B, keeps 16B align)

typedef __attribute__((ext_vector_type(8))) short bf16x8;  // MFMA A/B frag (8 bf16, 4 VGPRs)
typedef __attribute__((ext_vector_type(4))) float f32x4;   // MFMA C/D frag

__device__ inline short f2bf(float x) {
  // fp32 -> bf16 RNE
  union { float f; unsigned u; } a; a.f = x;
  unsigned r = a.u + 0x7fffu + ((a.u >> 16) & 1u);
  return (short)(r >> 16);
}

__device__ inline float fast_tanh(float x) {
  // tanh(x) = 1 - 2/(exp(2x)+1); exp(2x) = exp2(x * 2*log2(e))
  // large +x -> e=inf -> rcp=0 -> 1 ; large -x -> e=0 -> 1-2*1 = -1. Correct limits.
  float e = __builtin_amdgcn_exp2f(x * 2.885390081777927f);
  return 1.0f - 2.0f * __builtin_amdgcn_rcpf(e + 1.0f);
}

} // namespace

// One block = one (b,h) x 64-row Q tile. 4 waves, wave w owns rows [16w,16w+16).
// K-loop over 32 tiles of 64 key positions:
//   S = tanh(scale * Q K^T) * !mask   (MFMA 16x16x32 bf16, C-layout regs)
//   O += S V                          (S via LDS round-trip C-layout -> A-layout)
__global__ __launch_bounds__(256) void attn_tanh_kernel(
    const float* __restrict__ Q, const float* __restrict__ K,
    const float* __restrict__ V, const int* __restrict__ M,
    float* __restrict__ O)
{
  __shared__ __align__(16) short q_s[64 * LSTR];
  __shared__ __align__(16) short k_s[64 * LSTR];
  __shared__ __align__(16) short vt_s[64 * LSTR];   // V transposed: [d][kpos]
  __shared__ __align__(16) short s_s[64 * LSTR];

  const int tid  = threadIdx.x;
  const int wave = tid >> 6;
  const int lane = tid & 63;
  const int l15  = lane & 15;
  const int quad = lane >> 4;

  const int bh = blockIdx.x >> 5;          // 32 q-tiles per (b,h)
  const int q0 = (blockIdx.x & 31) * 64;

  const float* qp = Q + (size_t)bh * N * D;
  const float* kp = K + (size_t)bh * N * D;
  const float* vp = V + (size_t)bh * N * D;
  const int* mp = M + (size_t)bh * N * N;
  float* op = O + (size_t)bh * N * D;

  // ---- stage Q tile (64x64 fp32 -> bf16 LDS, row-major) ----
#pragma unroll
  for (int i = 0; i < 4; ++i) {
    int idx = i * 256 + tid;           // 1024 float4 slots
    int row = idx >> 4;
    int c4  = (idx & 15) << 2;
    float4 f = *(const float4*)(qp + (q0 + row) * D + c4);
    short* d = &q_s[row * LSTR + c4];
    d[0] = f2bf(f.x); d[1] = f2bf(f.y); d[2] = f2bf(f.z); d[3] = f2bf(f.w);
  }

  f32x4 o_acc[4];
#pragma unroll
  for (int i = 0; i < 4; ++i) o_acc[i] = (f32x4){0.f, 0.f, 0.f, 0.f};

  const int mrow = q0 + wave * 16 + quad * 4;   // + r gives the global q row

  for (int kt = 0; kt < N / 64; ++kt) {
    __syncthreads();   // previous iteration's readers of k_s/vt_s are done

    // ---- stage K tile (row-major) and V tile (transposed) ----
#pragma unroll
    for (int i = 0; i < 4; ++i) {
      int idx = i * 256 + tid;
      int row = idx >> 4;            // key position within tile
      int c4  = (idx & 15) << 2;     // d offset
      float4 f = *(const float4*)(kp + (kt * 64 + row) * D + c4);
      short* d = &k_s[row * LSTR + c4];
      d[0] = f2bf(f.x); d[1] = f2bf(f.y); d[2] = f2bf(f.z); d[3] = f2bf(f.w);
      float4 g = *(const float4*)(vp + (kt * 64 + row) * D + c4);
      vt_s[(c4 + 0) * LSTR + row] = f2bf(g.x);
      vt_s[(c4 + 1) * LSTR + row] = f2bf(g.y);
      vt_s[(c4 + 2) * LSTR + row] = f2bf(g.z);
      vt_s[(c4 + 3) * LSTR + row] = f2bf(g.w);
    }
    __syncthreads();

    // ---- S = tanh(scale * Q K^T), masked; wave-local 16x64 strip ----
    // A frag: A[m=l15][k=quad*8+j]  B frag: B[k=quad*8+j][n=l15] = K[n][k]
    const short* qrow_base = &q_s[(wave * 16 + l15) * LSTR + quad * 8];
#pragma unroll
    for (int ct = 0; ct < 4; ++ct) {
      f32x4 acc = {0.f, 0.f, 0.f, 0.f};
#pragma unroll
      for (int ks = 0; ks < 2; ++ks) {
        bf16x8 a = *(const bf16x8*)(qrow_base + ks * 32);
        bf16x8 b = *(const bf16x8*)(&k_s[(ct * 16 + l15) * LSTR + quad * 8 + ks * 32]);
        acc = __builtin_amdgcn_mfma_f32_16x16x32_bf16(a, b, acc, 0, 0, 0);
      }
      // C layout: col = l15, row = quad*4 + r  [m89-verified]
      const int* mptr = mp + (size_t)mrow * N + kt * 64 + ct * 16 + l15;
#pragma unroll
      for (int r = 0; r < 4; ++r) {
        float s = fast_tanh(acc[r] * SCALE);
        int mm = mptr[(size_t)r * N];
        s = mm ? 0.0f : s;
        s_s[(wave * 16 + quad * 4 + r) * LSTR + ct * 16 + l15] = f2bf(s);
      }
    }

    // ---- O += S * V  (wave reads only its own strip: no barrier needed) ----
    const short* srow_base = &s_s[(wave * 16 + l15) * LSTR + quad * 8];
#pragma unroll
    for (int ks = 0; ks < 2; ++ks) {
      bf16x8 a = *(const bf16x8*)(srow_base + ks * 32);
#pragma unroll
      for (int nt = 0; nt < 4; ++nt) {
        // B[k=kpos][n=d] = V[kpos][d] = vt_s[d][kpos]; lane reads 8 contiguous bf16 along kpos
        bf16x8 b = *(const bf16x8*)(&vt_s[(nt * 16 + l15) * LSTR + quad * 8 + ks * 32]);
        o_acc[nt] = __builtin_amdgcn_mfma_f32_16x16x32_bf16(a, b, o_acc[nt], 0, 0, 0);
      }
    }
  }

  // ---- write O (C layout: row = quad*4+r, col = nt*16+l15) ----
#pragma unroll
  for (int nt = 0; nt < 4; ++nt) {
#pragma unroll
    for (int r = 0; r < 4; ++r) {
      op[(q0 + wave * 16 + quad * 4 + r) * D + nt * 16 + l15] = o_acc[nt][r];
    }
  }
}

extern "C" void kernel_launch(void* const* d_in, const int* in_sizes, int n_in,
                              void* d_out, int out_size, void* d_ws, size_t ws_size,
                              hipStream_t stream) {
  const float* q = (const float*)d_in[0];
  const float* k = (const float*)d_in[1];
  const float* v = (const float*)d_in[2];
  const int* m = (const int*)d_in[3];   // harness promotes bool -> int32
  float* out = (float*)d_out;

  // B*H = 32 (b,h) pairs x 32 q-tiles of 64 rows = 1024 blocks
  attn_tanh_kernel<<<dim3(1024), dim3(256), 0, stream>>>(q, k, v, m, out);
}

// Round 3
// 759.295 us; speedup vs baseline: 1.2937x; 1.2937x over previous
//
#include <hip/hip_runtime.h>
#include <hip/hip_bf16.h>

namespace {

constexpr int N = 2048;
constexpr int D = 64;
constexpr float SCALE = 0.125f;   // D^-0.5, D=64
constexpr int LSTR = 72;          // LDS row stride in bf16 elems (64 + 8 pad)
constexpr int NT = N / 64;        // 32 K-tiles

typedef __attribute__((ext_vector_type(8))) short bf16x8;  // MFMA A/B frag
typedef __attribute__((ext_vector_type(4))) float f32x4;   // MFMA C/D frag
typedef __attribute__((ext_vector_type(4))) short short4v; // packed b64 LDS store

__device__ inline short f2bf(float x) {
  union { float f; unsigned u; } a; a.f = x;
  unsigned r = a.u + 0x7fffu + ((a.u >> 16) & 1u);
  return (short)(r >> 16);
}

__device__ inline float fast_tanh(float x) {
  // tanh(x) = 1 - 2/(exp2(x*2log2e)+1); correct limits at +-inf
  float e = __builtin_amdgcn_exp2f(x * 2.885390081777927f);
  return 1.0f - 2.0f * __builtin_amdgcn_rcpf(e + 1.0f);
}

} // namespace

// One block = one (b,h) x 64-row Q tile; 4 waves, wave w owns rows [16w,16w+16).
// Software-pipelined: K/V-staging float4s and mask ints for tile kt+1 are
// loaded into registers during tile kt's compute (one latency/iter, not ~20).
__global__ __launch_bounds__(256) void attn_tanh_kernel(
    const float* __restrict__ Q, const float* __restrict__ K,
    const float* __restrict__ V, const int* __restrict__ M,
    float* __restrict__ O)
{
  __shared__ __align__(16) short k_s[64 * LSTR];
  __shared__ __align__(16) short vt_s[64 * LSTR];   // V transposed: [d][kpos]
  __shared__ __align__(16) short s_s[64 * LSTR];

  const int tid  = threadIdx.x;
  const int wave = tid >> 6;
  const int lane = tid & 63;
  const int l15  = lane & 15;
  const int quad = lane >> 4;

  const int bh = blockIdx.x >> 5;
  const int q0 = (blockIdx.x & 31) * 64;

  const float* qp = Q + (size_t)bh * N * D;
  const float* kp = K + (size_t)bh * N * D;
  const float* vp = V + (size_t)bh * N * D;
  const int*   mp = M + (size_t)bh * N * N;
  float* op = O + (size_t)bh * N * D;

  // ---- Q A-fragments straight to registers (held for all 32 tiles) ----
  bf16x8 qf[2];
  {
    const float* qrow = qp + (size_t)(q0 + wave * 16 + l15) * D + quad * 8;
#pragma unroll
    for (int ks = 0; ks < 2; ++ks) {
      float4 f0 = *(const float4*)(qrow + ks * 32);
      float4 f1 = *(const float4*)(qrow + ks * 32 + 4);
      bf16x8 t;
      t[0] = f2bf(f0.x); t[1] = f2bf(f0.y); t[2] = f2bf(f0.z); t[3] = f2bf(f0.w);
      t[4] = f2bf(f1.x); t[5] = f2bf(f1.y); t[6] = f2bf(f1.z); t[7] = f2bf(f1.w);
      qf[ks] = t;
    }
  }

  const int r0 = tid >> 4;         // staging row sub-index 0..15
  const int c4 = (tid & 15) << 2;  // staging d-offset 0,4,..,60

  float4 kreg[4], vreg[4];
  int mreg[16];
  const int* mbase = mp + (size_t)(q0 + wave * 16 + quad * 4) * N + l15;

  // ---- prologue: loads for tile 0 ----
#pragma unroll
  for (int i = 0; i < 4; ++i) {
    kreg[i] = *(const float4*)(kp + (size_t)(i * 16 + r0) * D + c4);
    vreg[i] = *(const float4*)(vp + (size_t)(i * 16 + r0) * D + c4);
  }
#pragma unroll
  for (int r = 0; r < 4; ++r)
#pragma unroll
    for (int ct = 0; ct < 4; ++ct)
      mreg[r * 4 + ct] = __builtin_nontemporal_load(mbase + (size_t)r * N + ct * 16);

  f32x4 o_acc[4];
#pragma unroll
  for (int i = 0; i < 4; ++i) o_acc[i] = (f32x4){0.f, 0.f, 0.f, 0.f};

  for (int kt = 0; kt < NT; ++kt) {
    __syncthreads();   // previous tile's LDS readers done

    // ---- write staged regs -> LDS ----
#pragma unroll
    for (int i = 0; i < 4; ++i) {
      int row = i * 16 + r0;
      short4v kv;
      kv[0] = f2bf(kreg[i].x); kv[1] = f2bf(kreg[i].y);
      kv[2] = f2bf(kreg[i].z); kv[3] = f2bf(kreg[i].w);
      *(short4v*)(&k_s[row * LSTR + c4]) = kv;
      vt_s[(c4 + 0) * LSTR + row] = f2bf(vreg[i].x);
      vt_s[(c4 + 1) * LSTR + row] = f2bf(vreg[i].y);
      vt_s[(c4 + 2) * LSTR + row] = f2bf(vreg[i].z);
      vt_s[(c4 + 3) * LSTR + row] = f2bf(vreg[i].w);
    }
    __syncthreads();

    // ---- S = tanh(scale * Q K^T) * !mask (mask already in regs) ----
#pragma unroll
    for (int ct = 0; ct < 4; ++ct) {
      f32x4 acc = {0.f, 0.f, 0.f, 0.f};
#pragma unroll
      for (int ks = 0; ks < 2; ++ks) {
        bf16x8 b = *(const bf16x8*)(&k_s[(ct * 16 + l15) * LSTR + quad * 8 + ks * 32]);
        acc = __builtin_amdgcn_mfma_f32_16x16x32_bf16(qf[ks], b, acc, 0, 0, 0);
      }
#pragma unroll
      for (int r = 0; r < 4; ++r) {
        float s = fast_tanh(acc[r] * SCALE);
        s = mreg[r * 4 + ct] ? 0.0f : s;
        s_s[(wave * 16 + quad * 4 + r) * LSTR + ct * 16 + l15] = f2bf(s);
      }
    }

    // ---- prefetch tile kt+1 into registers (issue only; consumed next iter) ----
    if (kt + 1 < NT) {
      const float* kpt = kp + (size_t)(kt + 1) * 64 * D;
      const float* vpt = vp + (size_t)(kt + 1) * 64 * D;
#pragma unroll
      for (int i = 0; i < 4; ++i) {
        kreg[i] = *(const float4*)(kpt + (size_t)(i * 16 + r0) * D + c4);
        vreg[i] = *(const float4*)(vpt + (size_t)(i * 16 + r0) * D + c4);
      }
      const int* mb = mbase + (size_t)(kt + 1) * 64;
#pragma unroll
      for (int r = 0; r < 4; ++r)
#pragma unroll
        for (int ct = 0; ct < 4; ++ct)
          mreg[r * 4 + ct] = __builtin_nontemporal_load(mb + (size_t)r * N + ct * 16);
    }

    // ---- O += S * V ----
    const short* srow = &s_s[(wave * 16 + l15) * LSTR + quad * 8];
#pragma unroll
    for (int ks = 0; ks < 2; ++ks) {
      bf16x8 a = *(const bf16x8*)(srow + ks * 32);
#pragma unroll
      for (int nt = 0; nt < 4; ++nt) {
        bf16x8 b = *(const bf16x8*)(&vt_s[(nt * 16 + l15) * LSTR + quad * 8 + ks * 32]);
        o_acc[nt] = __builtin_amdgcn_mfma_f32_16x16x32_bf16(a, b, o_acc[nt], 0, 0, 0);
      }
    }
  }

  // ---- write O (C layout: row = quad*4+r, col = nt*16+l15) ----
#pragma unroll
  for (int nt = 0; nt < 4; ++nt) {
#pragma unroll
    for (int r = 0; r < 4; ++r) {
      op[(q0 + wave * 16 + quad * 4 + r) * D + nt * 16 + l15] = o_acc[nt][r];
    }
  }
}

extern "C" void kernel_launch(void* const* d_in, const int* in_sizes, int n_in,
                              void* d_out, int out_size, void* d_ws, size_t ws_size,
                              hipStream_t stream) {
  const float* q = (const float*)d_in[0];
  const float* k = (const float*)d_in[1];
  const float* v = (const float*)d_in[2];
  const int* m = (const int*)d_in[3];   // harness promotes bool -> int32
  float* out = (float*)d_out;

  attn_tanh_kernel<<<dim3(1024), dim3(256), 0, stream>>>(q, k, v, m, out);
}

// Round 4
// 758.452 us; speedup vs baseline: 1.2951x; 1.0011x over previous
//
#include <hip/hip_runtime.h>

namespace {

constexpr int N = 2048;
constexpr int D = 64;
constexpr float SCALE = 0.125f;   // D^-0.5
constexpr int LK = 72;            // k_s / s_s row stride (shorts): 16B-aligned rows for b128 reads
constexpr int LV = 68;            // vt_s row stride (shorts): 8B-aligned rows, bank step 2 per row
constexpr int NT = N / 64;        // 32 K-tiles

typedef __attribute__((ext_vector_type(8))) short bf16x8;   // MFMA A/B frag
typedef __attribute__((ext_vector_type(4))) short short4v;  // b64 LDS packet
typedef __attribute__((ext_vector_type(4))) float f32x4;    // MFMA C/D frag
typedef __attribute__((ext_vector_type(4))) int   int4v;    // mask packet

__device__ inline short f2bf(float x) {
  union { float f; unsigned u; } a; a.f = x;
  unsigned r = a.u + 0x7fffu + ((a.u >> 16) & 1u);
  return (short)(r >> 16);
}

__device__ inline float fast_tanh(float x) {
  // tanh(x) = 1 - 2/(exp2(x*2log2e)+1); correct limits at +-inf
  float e = __builtin_amdgcn_exp2f(x * 2.885390081777927f);
  return 1.0f - 2.0f * __builtin_amdgcn_rcpf(e + 1.0f);
}

} // namespace

// One block = one (b,h) x 64-row Q tile; 4 waves, wave w owns q rows [16w,16w+16).
// S is computed TRANSPOSED (S^T = K Q^T via operand swap: A/B frags have identical
// lane layouts over row-major tiles), so the 4 C-regs per lane are 4 consecutive kp:
// S-writes pack to conflict-free ds_write_b64 and mask loads become dwordx4.
__global__ __launch_bounds__(256) void attn_tanh_kernel(
    const float* __restrict__ Q, const float* __restrict__ K,
    const float* __restrict__ V, const int* __restrict__ M,
    float* __restrict__ O)
{
  __shared__ __align__(16) short k_s[64 * LK];
  __shared__ __align__(16) short s_s[64 * LK];
  __shared__ __align__(16) short vt_s[64 * LV];   // V transposed: [d][kpos]

  const int tid  = threadIdx.x;
  const int wave = tid >> 6;
  const int lane = tid & 63;
  const int l15  = lane & 15;
  const int quad = lane >> 4;

  const int bh = blockIdx.x >> 5;
  const int q0 = (blockIdx.x & 31) * 64;

  const float* qp = Q + (size_t)bh * N * D;
  const float* kp = K + (size_t)bh * N * D;
  const float* vp = V + (size_t)bh * N * D;
  const int*   mp = M + (size_t)bh * N * N;
  float* op = O + (size_t)bh * N * D;

  // ---- Q A/B-fragments in registers for all 32 tiles ----
  bf16x8 qf[2];
  {
    const float* qrow = qp + (size_t)(q0 + wave * 16 + l15) * D + quad * 8;
#pragma unroll
    for (int ks = 0; ks < 2; ++ks) {
      float4 f0 = *(const float4*)(qrow + ks * 32);
      float4 f1 = *(const float4*)(qrow + ks * 32 + 4);
      bf16x8 t;
      t[0] = f2bf(f0.x); t[1] = f2bf(f0.y); t[2] = f2bf(f0.z); t[3] = f2bf(f0.w);
      t[4] = f2bf(f1.x); t[5] = f2bf(f1.y); t[6] = f2bf(f1.z); t[7] = f2bf(f1.w);
      qf[ks] = t;
    }
  }

  const int r0 = tid >> 4;         // K staging row sub-index 0..15
  const int c4 = (tid & 15) << 2;  // K staging d-offset

  float4 kreg[4];
  float  vreg[16];                 // V: lane=d, 16 consecutive kp rows (wave*16+i)
  int4v  mreg[4];

  const float* vbase = vp + (size_t)(wave * 16) * D + lane;
  const int*   mbase = mp + (size_t)(q0 + wave * 16 + l15) * N + quad * 4;

  // ---- prologue: loads for tile 0 ----
#pragma unroll
  for (int i = 0; i < 4; ++i)
    kreg[i] = *(const float4*)(kp + (size_t)(i * 16 + r0) * D + c4);
#pragma unroll
  for (int i = 0; i < 16; ++i)
    vreg[i] = vbase[(size_t)i * D];
#pragma unroll
  for (int ct = 0; ct < 4; ++ct)
    mreg[ct] = __builtin_nontemporal_load((const int4v*)(mbase + ct * 16));

  f32x4 o_acc[4];
#pragma unroll
  for (int i = 0; i < 4; ++i) o_acc[i] = (f32x4){0.f, 0.f, 0.f, 0.f};

  for (int kt = 0; kt < NT; ++kt) {
    __syncthreads();   // previous tile's k_s/vt_s readers done

    // ---- staged regs -> LDS (all b64, low-conflict) ----
#pragma unroll
    for (int i = 0; i < 4; ++i) {
      short4v kv;
      kv[0] = f2bf(kreg[i].x); kv[1] = f2bf(kreg[i].y);
      kv[2] = f2bf(kreg[i].z); kv[3] = f2bf(kreg[i].w);
      *(short4v*)(&k_s[(i * 16 + r0) * LK + c4]) = kv;
    }
#pragma unroll
    for (int c = 0; c < 4; ++c) {
      short4v vv;
      vv[0] = f2bf(vreg[4 * c + 0]); vv[1] = f2bf(vreg[4 * c + 1]);
      vv[2] = f2bf(vreg[4 * c + 2]); vv[3] = f2bf(vreg[4 * c + 3]);
      *(short4v*)(&vt_s[lane * LV + wave * 16 + 4 * c]) = vv;
    }
    __syncthreads();

    // ---- S^T = K Q^T (operand swap), tanh, mask; b64-packed S write ----
#pragma unroll
    for (int ct = 0; ct < 4; ++ct) {
      f32x4 acc = {0.f, 0.f, 0.f, 0.f};
#pragma unroll
      for (int ks = 0; ks < 2; ++ks) {
        bf16x8 a = *(const bf16x8*)(&k_s[(ct * 16 + l15) * LK + ks * 32 + quad * 8]);
        acc = __builtin_amdgcn_mfma_f32_16x16x32_bf16(a, qf[ks], acc, 0, 0, 0);
      }
      // C layout of S^T: lane(quad,l15) reg r = S[q=l15][kp=ct*16+quad*4+r]
      short4v sv;
#pragma unroll
      for (int r = 0; r < 4; ++r) {
        float s = fast_tanh(acc[r] * SCALE);
        sv[r] = mreg[ct][r] ? (short)0 : f2bf(s);
      }
      *(short4v*)(&s_s[(wave * 16 + l15) * LK + ct * 16 + quad * 4]) = sv;
    }

    // ---- prefetch tile kt+1 (issue only; consumed next iteration) ----
    if (kt + 1 < NT) {
      const float* kpt = kp + (size_t)(kt + 1) * 64 * D;
#pragma unroll
      for (int i = 0; i < 4; ++i)
        kreg[i] = *(const float4*)(kpt + (size_t)(i * 16 + r0) * D + c4);
      const float* vpt = vbase + (size_t)(kt + 1) * 64 * D;
#pragma unroll
      for (int i = 0; i < 16; ++i)
        vreg[i] = vpt[(size_t)i * D];
      const int* mb = mbase + (size_t)(kt + 1) * 64;
#pragma unroll
      for (int ct = 0; ct < 4; ++ct)
        mreg[ct] = __builtin_nontemporal_load((const int4v*)(mb + ct * 16));
    }

    // ---- O += S V ----
#pragma unroll
    for (int ks = 0; ks < 2; ++ks) {
      bf16x8 a = *(const bf16x8*)(&s_s[(wave * 16 + l15) * LK + ks * 32 + quad * 8]);
#pragma unroll
      for (int nt = 0; nt < 4; ++nt) {
        const short* vb = &vt_s[(nt * 16 + l15) * LV + ks * 32 + quad * 8];
        short4v lo = *(const short4v*)(vb);
        short4v hi = *(const short4v*)(vb + 4);
        bf16x8 b = __builtin_shufflevector(lo, hi, 0, 1, 2, 3, 4, 5, 6, 7);
        o_acc[nt] = __builtin_amdgcn_mfma_f32_16x16x32_bf16(a, b, o_acc[nt], 0, 0, 0);
      }
    }
  }

  // ---- write O (C layout: row q = quad*4+r, col d = nt*16+l15) ----
#pragma unroll
  for (int nt = 0; nt < 4; ++nt) {
#pragma unroll
    for (int r = 0; r < 4; ++r) {
      op[(q0 + wave * 16 + quad * 4 + r) * D + nt * 16 + l15] = o_acc[nt][r];
    }
  }
}

extern "C" void kernel_launch(void* const* d_in, const int* in_sizes, int n_in,
                              void* d_out, int out_size, void* d_ws, size_t ws_size,
                              hipStream_t stream) {
  const float* q = (const float*)d_in[0];
  const float* k = (const float*)d_in[1];
  const float* v = (const float*)d_in[2];
  const int* m = (const int*)d_in[3];   // harness promotes bool -> int32
  float* out = (float*)d_out;

  attn_tanh_kernel<<<dim3(1024), dim3(256), 0, stream>>>(q, k, v, m, out);
}